// Round 8
// baseline (363.135 us; speedup 1.0000x reference)
//
#include <hip/hip_runtime.h>
#include <math.h>

#define N_NODES 50000
#define N_EDGES 800000
#define N_GRAPHS 512
#define D 64
#define D_CLS 128
#define BNODES 128                       // dst nodes per bucket
#define NBUK 391                         // cdiv(N_NODES, BNODES)
#define PART_TILE 4096                   // edges per k_part block (256 thr x 16)

typedef float vfloat4 __attribute__((ext_vector_type(4)));

static inline int cdiv(int a, int b) { return (a + b - 1) / b; }

// ---------- zero ----------

__global__ void k_zero(int* __restrict__ p, int nwords) {
    int i = blockIdx.x * blockDim.x + threadIdx.x;
    if (i < nwords) p[i] = 0;
}

// ---------- degree histogram (per node) ----------

__global__ void k_hist(const int* __restrict__ dst, int* __restrict__ cnt) {
    int e = blockIdx.x * blockDim.x + threadIdx.x;
    if (e < N_EDGES) atomicAdd(&cnt[dst[e]], 1);
}

// ---------- row_ptr scan (196 blocks of 256); also emits dis ----------

__global__ void k_scan1(const int* __restrict__ cnt, int* __restrict__ bsum,
                        float* __restrict__ dis) {
    __shared__ int s[256];
    int i = blockIdx.x * 256 + threadIdx.x;
    int v = 0;
    if (i < N_NODES) {
        v = cnt[i];
        dis[i] = 1.0f / sqrtf((float)v + 1.0f);
    }
    s[threadIdx.x] = v;
    __syncthreads();
    for (int off = 128; off > 0; off >>= 1) {
        if (threadIdx.x < off) s[threadIdx.x] += s[threadIdx.x + off];
        __syncthreads();
    }
    if (threadIdx.x == 0) bsum[blockIdx.x] = s[0];
}

__global__ void k_scan2(int* bsum, int nb) {
    __shared__ int s[256];
    int t = threadIdx.x;
    int v = (t < nb) ? bsum[t] : 0;
    s[t] = v;
    __syncthreads();
    for (int off = 1; off < 256; off <<= 1) {
        int x = (t >= off) ? s[t - off] : 0;
        __syncthreads();
        s[t] += x;
        __syncthreads();
    }
    if (t < nb) bsum[t] = s[t] - v;
}

__global__ void k_scan3(const int* __restrict__ cnt, const int* __restrict__ bsum,
                        int* __restrict__ row_ptr) {
    __shared__ int s[256];
    int i = blockIdx.x * 256 + threadIdx.x;
    int v = (i < N_NODES) ? cnt[i] : 0;
    s[threadIdx.x] = v;
    __syncthreads();
    for (int off = 1; off < 256; off <<= 1) {
        int x = (threadIdx.x >= off) ? s[threadIdx.x - off] : 0;
        __syncthreads();
        s[threadIdx.x] += x;
        __syncthreads();
    }
    if (i < N_NODES) row_ptr[i] = bsum[blockIdx.x] + s[threadIdx.x] - v;
    if (i == 0) row_ptr[N_NODES] = N_EDGES;
}

__global__ void k_binit(const int* __restrict__ row_ptr, int* __restrict__ btail) {
    int b = blockIdx.x * blockDim.x + threadIdx.x;
    if (b < NBUK) btail[b] = row_ptr[b * BNODES];
}

// ---------- partition edges into buckets (LDS histogram, 1 atomic/(blk,buk)) ----

__global__ __launch_bounds__(256) void k_part(
        const int* __restrict__ src, const int* __restrict__ dst,
        int* __restrict__ btail, int* __restrict__ ebuf) {
    __shared__ int lcnt[NBUK];
    __shared__ int lbase[NBUK];
    int t = threadIdx.x;
    for (int i = t; i < NBUK; i += 256) lcnt[i] = 0;
    __syncthreads();

    int e0 = blockIdx.x * PART_TILE + t;
    int ent[16];
    int br[16];
    #pragma unroll
    for (int k = 0; k < 16; k++) {
        int e = e0 + k * 256;
        if (e < N_EDGES) {
            int d = dst[e];
            int b = d / BNODES;
            int r = atomicAdd(&lcnt[b], 1);
            ent[k] = src[e] | ((d & (BNODES - 1)) << 16);  // src(16b)|dlocal(7b)
            br[k] = (b << 16) | r;                          // r < 4096
        } else {
            br[k] = -1;
        }
    }
    __syncthreads();
    for (int i = t; i < NBUK; i += 256) {
        int c = lcnt[i];
        lbase[i] = c ? atomicAdd(&btail[i], c) : 0;
    }
    __syncthreads();
    #pragma unroll
    for (int k = 0; k < 16; k++) {
        if (br[k] >= 0) {
            int b = br[k] >> 16, r = br[k] & 0xFFFF;
            ebuf[lbase[b] + r] = ent[k];
        }
    }
}

// ---------- exact CSR placement; writes confined to ~8KB bucket region ----------

__global__ __launch_bounds__(256) void k_place(
        const int* __restrict__ ebuf, const int* __restrict__ row_ptr,
        int* __restrict__ cnt, int* __restrict__ col) {
    int b = blockIdx.x;
    int n0 = b * BNODES;
    int nhi = n0 + BNODES;
    if (nhi > N_NODES) nhi = N_NODES;
    int s = row_ptr[n0];
    int e = row_ptr[nhi];
    for (int i = s + threadIdx.x; i < e; i += 256) {
        int v = ebuf[i];
        int d = n0 | (v >> 16);
        int pos = row_ptr[d] + atomicSub(&cnt[d], 1) - 1;
        col[pos] = v & 0xFFFF;
    }
}

// ---------- GEMM (X @ W) with dis-row-scaling fused: G = dis ⊙ (X @ W) ----------

#define XS_STRIDE 68   // 64 + 4 pad, keeps 16B alignment for float4 LDS ops

__global__ __launch_bounds__(256) void k_gemm_scale(
        const float* __restrict__ X, const float* __restrict__ W,
        const float* __restrict__ dis, float* __restrict__ G) {
    __shared__ float Xs[64 * XS_STRIDE];
    __shared__ float Ws[64 * 64];
    int n0 = blockIdx.x * 64;
    int t = threadIdx.x;

    {
        int base = t * 16;
        const float4* wsrc = (const float4*)(W + base);
        float4* wdst = (float4*)(Ws + base);
        wdst[0] = wsrc[0]; wdst[1] = wsrc[1]; wdst[2] = wsrc[2]; wdst[3] = wsrc[3];
    }
    {
        int row = t >> 2;
        int c0 = (t & 3) * 16;
        int grow = n0 + row;
        float4* xd = (float4*)(Xs + row * XS_STRIDE + c0);
        if (grow < N_NODES) {
            const float4* xp = (const float4*)(X + (size_t)grow * D + c0);
            xd[0] = xp[0]; xd[1] = xp[1]; xd[2] = xp[2]; xd[3] = xp[3];
        } else {
            float4 z = {0.f, 0.f, 0.f, 0.f};
            xd[0] = z; xd[1] = z; xd[2] = z; xd[3] = z;
        }
    }
    __syncthreads();

    int tc = t & 15, tr = t >> 4;
    int r0 = tr * 4, c0 = tc * 4;
    float acc[4][4] = {};
    #pragma unroll 4
    for (int k = 0; k < 64; k++) {
        float4 wv = *(const float4*)&Ws[k * 64 + c0];
        #pragma unroll
        for (int i = 0; i < 4; i++) {
            float xv = Xs[(r0 + i) * XS_STRIDE + k];
            acc[i][0] = fmaf(xv, wv.x, acc[i][0]);
            acc[i][1] = fmaf(xv, wv.y, acc[i][1]);
            acc[i][2] = fmaf(xv, wv.z, acc[i][2]);
            acc[i][3] = fmaf(xv, wv.w, acc[i][3]);
        }
    }
    #pragma unroll
    for (int i = 0; i < 4; i++) {
        int grow = n0 + r0 + i;
        if (grow < N_NODES) {
            float dsc = dis[grow];
            float4 o;
            o.x = acc[i][0] * dsc; o.y = acc[i][1] * dsc;
            o.z = acc[i][2] * dsc; o.w = acc[i][3] * dsc;
            *(float4*)&G[(size_t)grow * D + c0] = o;
        }
    }
}

// ---------- aggregation, feature-striped: pass touches 16 feats = one 64B line
// per row -> 3.2MB stripe fits one XCD L2. col reads / Out writes nontemporal
// so they don't evict the stripe. 4 lanes x float4 per node, 8-deep walk.

template<int FOFF>
__global__ __launch_bounds__(256) void k_aggp(
        const float* __restrict__ G, const int* __restrict__ row_ptr,
        const int* __restrict__ col, const float* __restrict__ dis,
        const float* __restrict__ bias, float* __restrict__ Out) {
    int t = threadIdx.x;
    int grp = t >> 2;                  // 64 node-groups per block
    int fl4 = FOFF + (t & 3) * 4;      // feature float4 offset within stripe
    int n = blockIdx.x * 64 + grp;
    if (n >= N_NODES) return;

    int s = row_ptr[n], e = row_ptr[n + 1];
    vfloat4 acc = *(const vfloat4*)(G + (size_t)n * D + fl4);   // self term

    for (int i = s; i < e; i += 8) {
        int i1 = i + 1, i2 = i + 2, i3 = i + 3;
        int i4 = i + 4, i5 = i + 5, i6 = i + 6, i7 = i + 7;
        int c0 = __builtin_nontemporal_load(col + i);
        int c1 = __builtin_nontemporal_load(col + (i1 < e ? i1 : i));
        int c2 = __builtin_nontemporal_load(col + (i2 < e ? i2 : i));
        int c3 = __builtin_nontemporal_load(col + (i3 < e ? i3 : i));
        int c4 = __builtin_nontemporal_load(col + (i4 < e ? i4 : i));
        int c5 = __builtin_nontemporal_load(col + (i5 < e ? i5 : i));
        int c6 = __builtin_nontemporal_load(col + (i6 < e ? i6 : i));
        int c7 = __builtin_nontemporal_load(col + (i7 < e ? i7 : i));
        float f1 = (i1 < e) ? 1.f : 0.f;
        float f2 = (i2 < e) ? 1.f : 0.f;
        float f3 = (i3 < e) ? 1.f : 0.f;
        float f4 = (i4 < e) ? 1.f : 0.f;
        float f5 = (i5 < e) ? 1.f : 0.f;
        float f6 = (i6 < e) ? 1.f : 0.f;
        float f7 = (i7 < e) ? 1.f : 0.f;
        vfloat4 g0 = *(const vfloat4*)(G + (size_t)c0 * D + fl4);
        vfloat4 g1 = *(const vfloat4*)(G + (size_t)c1 * D + fl4);
        vfloat4 g2 = *(const vfloat4*)(G + (size_t)c2 * D + fl4);
        vfloat4 g3 = *(const vfloat4*)(G + (size_t)c3 * D + fl4);
        vfloat4 g4 = *(const vfloat4*)(G + (size_t)c4 * D + fl4);
        vfloat4 g5 = *(const vfloat4*)(G + (size_t)c5 * D + fl4);
        vfloat4 g6 = *(const vfloat4*)(G + (size_t)c6 * D + fl4);
        vfloat4 g7 = *(const vfloat4*)(G + (size_t)c7 * D + fl4);
        acc += g0;
        acc += f1 * g1;
        acc += f2 * g2;
        acc += f3 * g3;
        acc += f4 * g4;
        acc += f5 * g5;
        acc += f6 * g6;
        acc += f7 * g7;
    }

    float dsc = dis[n];
    vfloat4 bv = *(const vfloat4*)(bias + fl4);
    vfloat4 o = dsc * acc + bv;
    __builtin_nontemporal_store(o, (vfloat4*)(Out + (size_t)n * D + fl4));
}

// ---------- pooling ----------

__global__ void k_bounds(const int* __restrict__ batch, int* __restrict__ start) {
    int g = blockIdx.x * blockDim.x + threadIdx.x;
    if (g <= N_GRAPHS) {
        int lo = 0, hi = N_NODES;
        while (lo < hi) {
            int mid = (lo + hi) >> 1;
            if (batch[mid] < g) lo = mid + 1; else hi = mid;
        }
        start[g] = lo;
    }
}

__global__ __launch_bounds__(256) void k_pool(
        const float* __restrict__ H, const int* __restrict__ start,
        float* __restrict__ P) {
    int g = blockIdx.x * 4 + (threadIdx.x >> 6);
    if (g >= N_GRAPHS) return;
    int lane = threadIdx.x & 63;
    int es  = lane >> 4;
    int fg4 = (lane & 15) * 4;
    int s = start[g], e = start[g + 1];
    float4 acc = {0.f, 0.f, 0.f, 0.f};
    for (int r = s + es; r < e; r += 4) {
        float4 h = *(const float4*)(H + (size_t)r * D + fg4);
        acc.x += h.x; acc.y += h.y; acc.z += h.z; acc.w += h.w;
    }
    #pragma unroll
    for (int m = 16; m < 64; m <<= 1) {
        acc.x += __shfl_xor(acc.x, m, 64);
        acc.y += __shfl_xor(acc.y, m, 64);
        acc.z += __shfl_xor(acc.z, m, 64);
        acc.w += __shfl_xor(acc.w, m, 64);
    }
    int cntr = e - s;
    float inv = 1.0f / (float)(cntr > 0 ? cntr : 1);
    if (es == 0) {
        float4 o;
        o.x = acc.x * inv; o.y = acc.y * inv; o.z = acc.z * inv; o.w = acc.w * inv;
        *(float4*)(P + g * D + fg4) = o;
    }
}

// ---------- classifier MLP ----------

__global__ __launch_bounds__(128) void k_mlp(
        const float* __restrict__ P,
        const float* __restrict__ w1, const float* __restrict__ b1,
        const float* __restrict__ w2, const float* __restrict__ b2,
        const float* __restrict__ fcw, const float* __restrict__ fcb,
        float* __restrict__ out) {
    __shared__ float ps[64];
    __shared__ float red[128];
    int g = blockIdx.x, t = threadIdx.x;
    if (t < 64) ps[t] = P[g * D + t];
    __syncthreads();
    float acc = b1[t];
    #pragma unroll
    for (int k = 0; k < 64; k++) acc = fmaf(ps[k], w1[k * D_CLS + t], acc);
    red[t] = acc * w2[t];
    __syncthreads();
    for (int s2 = 64; s2 > 0; s2 >>= 1) {
        if (t < s2) red[t] += red[t + s2];
        __syncthreads();
    }
    if (t == 0) {
        float o = red[0] + b2[0];
        o = fmaf(o, fcw[0], fcb[0]);
        out[g] = (o >= 0.f) ? o : 0.01f * o;
    }
}

// ---------- launch ----------

extern "C" void kernel_launch(void* const* d_in, const int* in_sizes, int n_in,
                              void* d_out, int out_size, void* d_ws, size_t ws_size,
                              hipStream_t stream) {
    const float* x   = (const float*)d_in[0];
    const float* W0  = (const float*)d_in[1];
    const float* b0  = (const float*)d_in[2];
    const float* W1  = (const float*)d_in[3];
    const float* b1  = (const float*)d_in[4];
    const float* W2  = (const float*)d_in[5];
    const float* b2  = (const float*)d_in[6];
    const float* l1w = (const float*)d_in[7];
    const float* l1b = (const float*)d_in[8];
    const float* l2w = (const float*)d_in[9];
    const float* l2b = (const float*)d_in[10];
    const float* fcw = (const float*)d_in[11];
    const float* fcb = (const float*)d_in[12];
    const int* eidx  = (const int*)d_in[13];
    const int* batch = (const int*)d_in[14];
    const int* src = eidx;
    const int* dst = eidx + N_EDGES;

    char* ws = (char*)d_ws;
    size_t off = 0;
    auto alloc = [&](size_t bytes) -> void* {
        off = (off + 255) & ~(size_t)255;
        void* p = ws + off;
        off += bytes;
        return p;
    };

    int*   row_ptr = (int*)  alloc((N_NODES + 1) * sizeof(int));
    int*   cnt     = (int*)  alloc(N_NODES * sizeof(int));
    int*   bsum    = (int*)  alloc(256 * sizeof(int));
    int*   btail   = (int*)  alloc(NBUK * sizeof(int));
    int*   ebuf    = (int*)  alloc(N_EDGES * sizeof(int));
    int*   col     = (int*)  alloc(N_EDGES * sizeof(int));
    float* dis     = (float*)alloc(N_NODES * sizeof(float));
    int*   start   = (int*)  alloc((N_GRAPHS + 1) * sizeof(int));
    float* bufA    = (float*)alloc((size_t)N_NODES * D * sizeof(float));
    float* bufB    = (float*)alloc((size_t)N_NODES * D * sizeof(float));
    float* bufC    = (float*)alloc((size_t)N_NODES * D * sizeof(float));
    float* pooled  = (float*)alloc((size_t)N_GRAPHS * D * sizeof(float));

    const int nbScan = cdiv(N_NODES, 256);   // 196
    const int nbE    = cdiv(N_EDGES, 256);   // 3125

    k_zero<<<nbScan, 256, 0, stream>>>(cnt, N_NODES);
    k_hist<<<nbE, 256, 0, stream>>>(dst, cnt);
    k_scan1<<<nbScan, 256, 0, stream>>>(cnt, bsum, dis);
    k_scan2<<<1, 256, 0, stream>>>(bsum, nbScan);
    k_scan3<<<nbScan, 256, 0, stream>>>(cnt, bsum, row_ptr);
    k_binit<<<cdiv(NBUK, 256), 256, 0, stream>>>(row_ptr, btail);
    k_part<<<cdiv(N_EDGES, PART_TILE), 256, 0, stream>>>(src, dst, btail, ebuf);
    k_place<<<NBUK, 256, 0, stream>>>(ebuf, row_ptr, cnt, col);

    const int nbGemm = cdiv(N_NODES, 64);    // 782
    const int nbAgg  = cdiv(N_NODES, 64);    // 782 (64 nodes per block)

    auto agg_layer = [&](const float* G, const float* bias, float* Out) {
        k_aggp<0><<<nbAgg, 256, 0, stream>>>(G, row_ptr, col, dis, bias, Out);
        k_aggp<16><<<nbAgg, 256, 0, stream>>>(G, row_ptr, col, dis, bias, Out);
        k_aggp<32><<<nbAgg, 256, 0, stream>>>(G, row_ptr, col, dis, bias, Out);
        k_aggp<48><<<nbAgg, 256, 0, stream>>>(G, row_ptr, col, dis, bias, Out);
    };

    // layer 0: x -> B
    k_gemm_scale<<<nbGemm, 256, 0, stream>>>(x, W0, dis, bufA);
    agg_layer(bufA, b0, bufB);
    // layer 1: B -> C
    k_gemm_scale<<<nbGemm, 256, 0, stream>>>(bufB, W1, dis, bufA);
    agg_layer(bufA, b1, bufC);
    // layer 2: C -> B
    k_gemm_scale<<<nbGemm, 256, 0, stream>>>(bufC, W2, dis, bufA);
    agg_layer(bufA, b2, bufB);

    k_bounds<<<cdiv(N_GRAPHS + 1, 256), 256, 0, stream>>>(batch, start);
    k_pool<<<cdiv(N_GRAPHS, 4), 256, 0, stream>>>(bufB, start, pooled);
    k_mlp<<<N_GRAPHS, 128, 0, stream>>>(pooled, l1w, l1b, l2w, l2b, fcw, fcb,
                                        (float*)d_out);
}

// Round 9
// 186.403 us; speedup vs baseline: 1.9481x; 1.9481x over previous
//
#include <hip/hip_runtime.h>
#include <math.h>

#define N_NODES 50000
#define N_EDGES 800000
#define N_GRAPHS 512
#define D 64
#define D_CLS 128
#define BNODES 128                       // dst nodes per bucket
#define NBUK 391                         // cdiv(N_NODES, BNODES)
#define PART_TILE 4096                   // edges per partition block (256 thr x 16)

static inline int cdiv(int a, int b) { return (a + b - 1) / b; }

// ---------- tiny zero ----------

__global__ void k_zero(int* __restrict__ p, int nwords) {
    int i = blockIdx.x * blockDim.x + threadIdx.x;
    if (i < nwords) p[i] = 0;
}

// ---------- bucket-level edge histogram (LDS; 1 global atomic/(blk,buk)) ------

__global__ __launch_bounds__(256) void k_bcount(
        const int* __restrict__ dst, int* __restrict__ bcnt) {
    __shared__ int lcnt[NBUK];
    int t = threadIdx.x;
    for (int i = t; i < NBUK; i += 256) lcnt[i] = 0;
    __syncthreads();
    int e0 = blockIdx.x * PART_TILE + t;
    #pragma unroll
    for (int k = 0; k < 16; k++) {
        int e = e0 + k * 256;
        if (e < N_EDGES) atomicAdd(&lcnt[dst[e] / BNODES], 1);
    }
    __syncthreads();
    for (int i = t; i < NBUK; i += 256) {
        int c = lcnt[i];
        if (c) atomicAdd(&bcnt[i], c);
    }
}

// ---------- scan bucket counts -> bbase[0..NBUK], btail ----------

__global__ __launch_bounds__(512) void k_bscan(
        const int* __restrict__ bcnt, int* __restrict__ bbase,
        int* __restrict__ btail) {
    __shared__ int s[512];
    int t = threadIdx.x;
    int v = (t < NBUK) ? bcnt[t] : 0;
    s[t] = v;
    __syncthreads();
    for (int off = 1; off < 512; off <<= 1) {
        int x = (t >= off) ? s[t - off] : 0;
        __syncthreads();
        s[t] += x;
        __syncthreads();
    }
    if (t < NBUK) {
        int ex = s[t] - v;
        bbase[t] = ex;
        btail[t] = ex;
    }
    if (t == NBUK - 1) bbase[NBUK] = s[t];   // == N_EDGES
}

// ---------- partition edges into buckets (LDS histogram, dense writes) --------

__global__ __launch_bounds__(256) void k_part(
        const int* __restrict__ src, const int* __restrict__ dst,
        int* __restrict__ btail, int* __restrict__ ebuf) {
    __shared__ int lcnt[NBUK];
    __shared__ int lbase[NBUK];
    int t = threadIdx.x;
    for (int i = t; i < NBUK; i += 256) lcnt[i] = 0;
    __syncthreads();

    int e0 = blockIdx.x * PART_TILE + t;
    int ent[16];
    int br[16];
    #pragma unroll
    for (int k = 0; k < 16; k++) {
        int e = e0 + k * 256;
        if (e < N_EDGES) {
            int d = dst[e];
            int b = d / BNODES;
            int r = atomicAdd(&lcnt[b], 1);
            ent[k] = src[e] | ((d & (BNODES - 1)) << 16);  // src(16b)|dlocal(7b)
            br[k] = (b << 16) | r;                          // r < 4096
        } else {
            br[k] = -1;
        }
    }
    __syncthreads();
    for (int i = t; i < NBUK; i += 256) {
        int c = lcnt[i];
        lbase[i] = c ? atomicAdd(&btail[i], c) : 0;
    }
    __syncthreads();
    #pragma unroll
    for (int k = 0; k < 16; k++) {
        if (br[k] >= 0) {
            int b = br[k] >> 16, r = br[k] & 0xFFFF;
            ebuf[lbase[b] + r] = ent[k];
        }
    }
}

// ---------- per-bucket CSR build: row_ptr, dis, node-sorted col ----------
// One block per bucket; two streaming passes over the contiguous ebuf slice
// (slice is L2-hot on pass 2). col writes confined to the ~8KB bucket region.

__global__ __launch_bounds__(256) void k_build(
        const int* __restrict__ ebuf, const int* __restrict__ bbase,
        int* __restrict__ row_ptr, float* __restrict__ dis,
        int* __restrict__ col) {
    __shared__ int hist[BNODES];
    __shared__ int base[BNODES];
    __shared__ int cur[BNODES];
    int t = threadIdx.x;
    int b = blockIdx.x;
    int s = bbase[b];
    int e = bbase[b + 1];

    if (t < BNODES) { hist[t] = 0; cur[t] = 0; }
    __syncthreads();

    // pass 1: per-node counts
    for (int i = s + t; i < e; i += 256)
        atomicAdd(&hist[(ebuf[i] >> 16) & (BNODES - 1)], 1);
    __syncthreads();

    // inclusive scan of hist into base
    if (t < BNODES) base[t] = hist[t];
    __syncthreads();
    for (int off = 1; off < BNODES; off <<= 1) {
        int x = 0;
        if (t < BNODES && t >= off) x = base[t - off];
        __syncthreads();
        if (t < BNODES) base[t] += x;
        __syncthreads();
    }
    // exclusive offsets + row_ptr/dis emit
    if (t < BNODES) {
        int ex = base[t] - hist[t];
        base[t] = ex;
        int n = b * BNODES + t;
        if (n < N_NODES) {
            row_ptr[n] = s + ex;
            dis[n] = rsqrtf((float)hist[t] + 1.0f);
        }
    }
    if (b == NBUK - 1 && t == 0) row_ptr[N_NODES] = N_EDGES;
    __syncthreads();

    // pass 2: place
    for (int i = s + t; i < e; i += 256) {
        int v = ebuf[i];
        int d = (v >> 16) & (BNODES - 1);
        int pos = atomicAdd(&cur[d], 1);
        col[s + base[d] + pos] = v & 0xFFFF;
    }
}

// ---------- GEMM (X @ W) with dis-row-scaling fused: G = dis ⊙ (X @ W) ----------

#define XS_STRIDE 68   // 64 + 4 pad, keeps 16B alignment for float4 LDS ops

__global__ __launch_bounds__(256) void k_gemm_scale(
        const float* __restrict__ X, const float* __restrict__ W,
        const float* __restrict__ dis, float* __restrict__ G) {
    __shared__ float Xs[64 * XS_STRIDE];
    __shared__ float Ws[64 * 64];
    int n0 = blockIdx.x * 64;
    int t = threadIdx.x;

    {
        int base = t * 16;
        const float4* wsrc = (const float4*)(W + base);
        float4* wdst = (float4*)(Ws + base);
        wdst[0] = wsrc[0]; wdst[1] = wsrc[1]; wdst[2] = wsrc[2]; wdst[3] = wsrc[3];
    }
    {
        int row = t >> 2;
        int c0 = (t & 3) * 16;
        int grow = n0 + row;
        float4* xd = (float4*)(Xs + row * XS_STRIDE + c0);
        if (grow < N_NODES) {
            const float4* xp = (const float4*)(X + (size_t)grow * D + c0);
            xd[0] = xp[0]; xd[1] = xp[1]; xd[2] = xp[2]; xd[3] = xp[3];
        } else {
            float4 z = {0.f, 0.f, 0.f, 0.f};
            xd[0] = z; xd[1] = z; xd[2] = z; xd[3] = z;
        }
    }
    __syncthreads();

    int tc = t & 15, tr = t >> 4;
    int r0 = tr * 4, c0 = tc * 4;
    float acc[4][4] = {};
    #pragma unroll 4
    for (int k = 0; k < 64; k++) {
        float4 wv = *(const float4*)&Ws[k * 64 + c0];
        #pragma unroll
        for (int i = 0; i < 4; i++) {
            float xv = Xs[(r0 + i) * XS_STRIDE + k];
            acc[i][0] = fmaf(xv, wv.x, acc[i][0]);
            acc[i][1] = fmaf(xv, wv.y, acc[i][1]);
            acc[i][2] = fmaf(xv, wv.z, acc[i][2]);
            acc[i][3] = fmaf(xv, wv.w, acc[i][3]);
        }
    }
    #pragma unroll
    for (int i = 0; i < 4; i++) {
        int grow = n0 + r0 + i;
        if (grow < N_NODES) {
            float dsc = dis[grow];
            float4 o;
            o.x = acc[i][0] * dsc; o.y = acc[i][1] * dsc;
            o.z = acc[i][2] * dsc; o.w = acc[i][3] * dsc;
            *(float4*)&G[(size_t)grow * D + c0] = o;
        }
    }
}

// ---------- aggregation (round-6 proven form): 16-lane group per node,
// 8-deep predicated edge walk, full 256B row gathers. ----------

__global__ __launch_bounds__(256) void k_agg(
        const float* __restrict__ G, const int* __restrict__ row_ptr,
        const int* __restrict__ col, const float* __restrict__ dis,
        const float* __restrict__ bias, float* __restrict__ Out) {
    int t = threadIdx.x;
    int grp = t >> 4;                 // 16 node-groups per block
    int fl4 = (t & 15) * 4;           // feature float4 offset
    int n = blockIdx.x * 16 + grp;    // grid = 3125 -> n < 50000 always

    int s = row_ptr[n], e = row_ptr[n + 1];
    float4 acc = *(const float4*)(G + (size_t)n * D + fl4);   // self term

    for (int i = s; i < e; i += 8) {
        int i1 = i + 1, i2 = i + 2, i3 = i + 3;
        int i4 = i + 4, i5 = i + 5, i6 = i + 6, i7 = i + 7;
        int c0 = col[i];
        int c1 = col[i1 < e ? i1 : i];
        int c2 = col[i2 < e ? i2 : i];
        int c3 = col[i3 < e ? i3 : i];
        int c4 = col[i4 < e ? i4 : i];
        int c5 = col[i5 < e ? i5 : i];
        int c6 = col[i6 < e ? i6 : i];
        int c7 = col[i7 < e ? i7 : i];
        float f1 = (i1 < e) ? 1.f : 0.f;
        float f2 = (i2 < e) ? 1.f : 0.f;
        float f3 = (i3 < e) ? 1.f : 0.f;
        float f4 = (i4 < e) ? 1.f : 0.f;
        float f5 = (i5 < e) ? 1.f : 0.f;
        float f6 = (i6 < e) ? 1.f : 0.f;
        float f7 = (i7 < e) ? 1.f : 0.f;
        float4 g0 = *(const float4*)(G + (size_t)c0 * D + fl4);
        float4 g1 = *(const float4*)(G + (size_t)c1 * D + fl4);
        float4 g2 = *(const float4*)(G + (size_t)c2 * D + fl4);
        float4 g3 = *(const float4*)(G + (size_t)c3 * D + fl4);
        float4 g4 = *(const float4*)(G + (size_t)c4 * D + fl4);
        float4 g5 = *(const float4*)(G + (size_t)c5 * D + fl4);
        float4 g6 = *(const float4*)(G + (size_t)c6 * D + fl4);
        float4 g7 = *(const float4*)(G + (size_t)c7 * D + fl4);
        acc.x += g0.x; acc.y += g0.y; acc.z += g0.z; acc.w += g0.w;
        acc.x = fmaf(f1, g1.x, acc.x); acc.y = fmaf(f1, g1.y, acc.y);
        acc.z = fmaf(f1, g1.z, acc.z); acc.w = fmaf(f1, g1.w, acc.w);
        acc.x = fmaf(f2, g2.x, acc.x); acc.y = fmaf(f2, g2.y, acc.y);
        acc.z = fmaf(f2, g2.z, acc.z); acc.w = fmaf(f2, g2.w, acc.w);
        acc.x = fmaf(f3, g3.x, acc.x); acc.y = fmaf(f3, g3.y, acc.y);
        acc.z = fmaf(f3, g3.z, acc.z); acc.w = fmaf(f3, g3.w, acc.w);
        acc.x = fmaf(f4, g4.x, acc.x); acc.y = fmaf(f4, g4.y, acc.y);
        acc.z = fmaf(f4, g4.z, acc.z); acc.w = fmaf(f4, g4.w, acc.w);
        acc.x = fmaf(f5, g5.x, acc.x); acc.y = fmaf(f5, g5.y, acc.y);
        acc.z = fmaf(f5, g5.z, acc.z); acc.w = fmaf(f5, g5.w, acc.w);
        acc.x = fmaf(f6, g6.x, acc.x); acc.y = fmaf(f6, g6.y, acc.y);
        acc.z = fmaf(f6, g6.z, acc.z); acc.w = fmaf(f6, g6.w, acc.w);
        acc.x = fmaf(f7, g7.x, acc.x); acc.y = fmaf(f7, g7.y, acc.y);
        acc.z = fmaf(f7, g7.z, acc.z); acc.w = fmaf(f7, g7.w, acc.w);
    }

    float dsc = dis[n];
    float4 bv = *(const float4*)(bias + fl4);
    float4 o;
    o.x = fmaf(dsc, acc.x, bv.x);
    o.y = fmaf(dsc, acc.y, bv.y);
    o.z = fmaf(dsc, acc.z, bv.z);
    o.w = fmaf(dsc, acc.w, bv.w);
    *(float4*)(Out + (size_t)n * D + fl4) = o;
}

// ---------- pooling (bounds fused via inline binary search) ----------

__device__ __forceinline__ int lower_bound_batch(const int* batch, int g) {
    int lo = 0, hi = N_NODES;
    while (lo < hi) {
        int mid = (lo + hi) >> 1;
        if (batch[mid] < g) lo = mid + 1; else hi = mid;
    }
    return lo;
}

__global__ __launch_bounds__(256) void k_pool(
        const float* __restrict__ H, const int* __restrict__ batch,
        float* __restrict__ P) {
    int g = blockIdx.x * 4 + (threadIdx.x >> 6);
    if (g >= N_GRAPHS) return;
    int lane = threadIdx.x & 63;
    int es  = lane >> 4;
    int fg4 = (lane & 15) * 4;
    int s = lower_bound_batch(batch, g);
    int e = lower_bound_batch(batch, g + 1);
    float4 acc = {0.f, 0.f, 0.f, 0.f};
    for (int r = s + es; r < e; r += 4) {
        float4 h = *(const float4*)(H + (size_t)r * D + fg4);
        acc.x += h.x; acc.y += h.y; acc.z += h.z; acc.w += h.w;
    }
    #pragma unroll
    for (int m = 16; m < 64; m <<= 1) {
        acc.x += __shfl_xor(acc.x, m, 64);
        acc.y += __shfl_xor(acc.y, m, 64);
        acc.z += __shfl_xor(acc.z, m, 64);
        acc.w += __shfl_xor(acc.w, m, 64);
    }
    int cntr = e - s;
    float inv = 1.0f / (float)(cntr > 0 ? cntr : 1);
    if (es == 0) {
        float4 o;
        o.x = acc.x * inv; o.y = acc.y * inv; o.z = acc.z * inv; o.w = acc.w * inv;
        *(float4*)(P + g * D + fg4) = o;
    }
}

// ---------- classifier MLP ----------

__global__ __launch_bounds__(128) void k_mlp(
        const float* __restrict__ P,
        const float* __restrict__ w1, const float* __restrict__ b1,
        const float* __restrict__ w2, const float* __restrict__ b2,
        const float* __restrict__ fcw, const float* __restrict__ fcb,
        float* __restrict__ out) {
    __shared__ float ps[64];
    __shared__ float red[128];
    int g = blockIdx.x, t = threadIdx.x;
    if (t < 64) ps[t] = P[g * D + t];
    __syncthreads();
    float acc = b1[t];
    #pragma unroll
    for (int k = 0; k < 64; k++) acc = fmaf(ps[k], w1[k * D_CLS + t], acc);
    red[t] = acc * w2[t];
    __syncthreads();
    for (int s2 = 64; s2 > 0; s2 >>= 1) {
        if (t < s2) red[t] += red[t + s2];
        __syncthreads();
    }
    if (t == 0) {
        float o = red[0] + b2[0];
        o = fmaf(o, fcw[0], fcb[0]);
        out[g] = (o >= 0.f) ? o : 0.01f * o;
    }
}

// ---------- launch ----------

extern "C" void kernel_launch(void* const* d_in, const int* in_sizes, int n_in,
                              void* d_out, int out_size, void* d_ws, size_t ws_size,
                              hipStream_t stream) {
    const float* x   = (const float*)d_in[0];
    const float* W0  = (const float*)d_in[1];
    const float* b0  = (const float*)d_in[2];
    const float* W1  = (const float*)d_in[3];
    const float* b1  = (const float*)d_in[4];
    const float* W2  = (const float*)d_in[5];
    const float* b2  = (const float*)d_in[6];
    const float* l1w = (const float*)d_in[7];
    const float* l1b = (const float*)d_in[8];
    const float* l2w = (const float*)d_in[9];
    const float* l2b = (const float*)d_in[10];
    const float* fcw = (const float*)d_in[11];
    const float* fcb = (const float*)d_in[12];
    const int* eidx  = (const int*)d_in[13];
    const int* batch = (const int*)d_in[14];
    const int* src = eidx;
    const int* dst = eidx + N_EDGES;

    char* ws = (char*)d_ws;
    size_t off = 0;
    auto alloc = [&](size_t bytes) -> void* {
        off = (off + 255) & ~(size_t)255;
        void* p = ws + off;
        off += bytes;
        return p;
    };

    int*   row_ptr = (int*)  alloc((N_NODES + 1) * sizeof(int));
    int*   bcnt    = (int*)  alloc(NBUK * sizeof(int));
    int*   bbase   = (int*)  alloc((NBUK + 1) * sizeof(int));
    int*   btail   = (int*)  alloc(NBUK * sizeof(int));
    int*   ebuf    = (int*)  alloc(N_EDGES * sizeof(int));
    int*   col     = (int*)  alloc(N_EDGES * sizeof(int));
    float* dis     = (float*)alloc(N_NODES * sizeof(float));
    float* bufA    = (float*)alloc((size_t)N_NODES * D * sizeof(float));
    float* bufB    = (float*)alloc((size_t)N_NODES * D * sizeof(float));
    float* bufC    = (float*)alloc((size_t)N_NODES * D * sizeof(float));
    float* pooled  = (float*)alloc((size_t)N_GRAPHS * D * sizeof(float));

    const int nbPart = cdiv(N_EDGES, PART_TILE);   // 196

    k_zero<<<cdiv(NBUK, 256), 256, 0, stream>>>(bcnt, NBUK);
    k_bcount<<<nbPart, 256, 0, stream>>>(dst, bcnt);
    k_bscan<<<1, 512, 0, stream>>>(bcnt, bbase, btail);
    k_part<<<nbPart, 256, 0, stream>>>(src, dst, btail, ebuf);
    k_build<<<NBUK, 256, 0, stream>>>(ebuf, bbase, row_ptr, dis, col);

    const int nbGemm = cdiv(N_NODES, 64);    // 782
    const int nbAgg  = cdiv(N_NODES, 16);    // 3125

    // layer 0: x -> B
    k_gemm_scale<<<nbGemm, 256, 0, stream>>>(x, W0, dis, bufA);
    k_agg<<<nbAgg, 256, 0, stream>>>(bufA, row_ptr, col, dis, b0, bufB);
    // layer 1: B -> C
    k_gemm_scale<<<nbGemm, 256, 0, stream>>>(bufB, W1, dis, bufA);
    k_agg<<<nbAgg, 256, 0, stream>>>(bufA, row_ptr, col, dis, b1, bufC);
    // layer 2: C -> B
    k_gemm_scale<<<nbGemm, 256, 0, stream>>>(bufC, W2, dis, bufA);
    k_agg<<<nbAgg, 256, 0, stream>>>(bufA, row_ptr, col, dis, b2, bufB);

    k_pool<<<cdiv(N_GRAPHS, 4), 256, 0, stream>>>(bufB, batch, pooled);
    k_mlp<<<N_GRAPHS, 128, 0, stream>>>(pooled, l1w, l1b, l2w, l2b, fcw, fcb,
                                        (float*)d_out);
}

// Round 10
// 143.739 us; speedup vs baseline: 2.5264x; 1.2968x over previous
//
#include <hip/hip_runtime.h>
#include <math.h>

#define N_NODES 50000
#define N_EDGES 800000
#define N_GRAPHS 512
#define D 64
#define D_CLS 128
#define BNODES 128                       // dst nodes per bucket
#define NBUK 391                         // cdiv(N_NODES, BNODES)
#define BSTRIDE 4096                     // padded slots per bucket (mean 2046, 45 sigma)
#define PART_TILE 4096                   // edges per partition block (256 thr x 16)

typedef _Float16 h4 __attribute__((ext_vector_type(4)));
typedef float    f4 __attribute__((ext_vector_type(4)));

static inline int cdiv(int a, int b) { return (a + b - 1) / b; }

// ---------- bucket tails init (padded layout: bucket b owns [b*BSTRIDE, ...)) --

__global__ void k_binit(int* __restrict__ btail) {
    int b = blockIdx.x * blockDim.x + threadIdx.x;
    if (b < NBUK) btail[b] = b * BSTRIDE;
}

// ---------- partition edges into buckets (LDS histogram, dense writes) --------

__global__ __launch_bounds__(256) void k_part(
        const int* __restrict__ src, const int* __restrict__ dst,
        int* __restrict__ btail, int* __restrict__ ebuf) {
    __shared__ int lcnt[NBUK];
    __shared__ int lbase[NBUK];
    int t = threadIdx.x;
    for (int i = t; i < NBUK; i += 256) lcnt[i] = 0;
    __syncthreads();

    int e0 = blockIdx.x * PART_TILE + t;
    int ent[16];
    int br[16];
    #pragma unroll
    for (int k = 0; k < 16; k++) {
        int e = e0 + k * 256;
        if (e < N_EDGES) {
            int d = dst[e];
            int b = d / BNODES;
            int r = atomicAdd(&lcnt[b], 1);
            ent[k] = src[e] | ((d & (BNODES - 1)) << 16);  // src(16b)|dlocal(7b)
            br[k] = (b << 16) | r;                          // r < 4096
        } else {
            br[k] = -1;
        }
    }
    __syncthreads();
    for (int i = t; i < NBUK; i += 256) {
        int c = lcnt[i];
        lbase[i] = c ? atomicAdd(&btail[i], c) : 0;
    }
    __syncthreads();
    #pragma unroll
    for (int k = 0; k < 16; k++) {
        if (br[k] >= 0) {
            int b = br[k] >> 16, r = br[k] & 0xFFFF;
            ebuf[lbase[b] + r] = ent[k];
        }
    }
}

// ---------- per-bucket CSR build: per-node [start,end), dis, node-sorted col --
// One block per bucket; bucket slice is contiguous (padded layout), L2-hot on
// pass 2; col writes confined to the bucket's 16KB region.

__global__ __launch_bounds__(256) void k_build(
        const int* __restrict__ ebuf, const int* __restrict__ btail,
        int* __restrict__ rstart, int* __restrict__ rend,
        float* __restrict__ dis, int* __restrict__ col) {
    __shared__ int hist[BNODES];
    __shared__ int base[BNODES];
    __shared__ int cur[BNODES];
    int t = threadIdx.x;
    int b = blockIdx.x;
    int s = b * BSTRIDE;
    int e = btail[b];

    if (t < BNODES) { hist[t] = 0; cur[t] = 0; }
    __syncthreads();

    // pass 1: per-node counts
    for (int i = s + t; i < e; i += 256)
        atomicAdd(&hist[(ebuf[i] >> 16) & (BNODES - 1)], 1);
    __syncthreads();

    // inclusive scan of hist into base
    if (t < BNODES) base[t] = hist[t];
    __syncthreads();
    for (int off = 1; off < BNODES; off <<= 1) {
        int x = 0;
        if (t < BNODES && t >= off) x = base[t - off];
        __syncthreads();
        if (t < BNODES) base[t] += x;
        __syncthreads();
    }
    if (t < BNODES) {
        int ex = base[t] - hist[t];
        base[t] = ex;
        int n = b * BNODES + t;
        if (n < N_NODES) {
            rstart[n] = s + ex;
            rend[n]   = s + ex + hist[t];
            dis[n] = rsqrtf((float)hist[t] + 1.0f);
        }
    }
    __syncthreads();

    // pass 2: place
    for (int i = s + t; i < e; i += 256) {
        int v = ebuf[i];
        int d = (v >> 16) & (BNODES - 1);
        int pos = atomicAdd(&cur[d], 1);
        col[s + base[d] + pos] = v & 0xFFFF;
    }
}

// ---------- GEMM: G16 = fp16( dis ⊙ (X @ W) ), f32 accumulate ----------

#define XS_STRIDE 68   // 64 + 4 pad, keeps 16B alignment for float4 LDS ops

__global__ __launch_bounds__(256) void k_gemm_scale(
        const float* __restrict__ X, const float* __restrict__ W,
        const float* __restrict__ dis, _Float16* __restrict__ G16) {
    __shared__ float Xs[64 * XS_STRIDE];
    __shared__ float Ws[64 * 64];
    int n0 = blockIdx.x * 64;
    int t = threadIdx.x;

    {
        int base = t * 16;
        const float4* wsrc = (const float4*)(W + base);
        float4* wdst = (float4*)(Ws + base);
        wdst[0] = wsrc[0]; wdst[1] = wsrc[1]; wdst[2] = wsrc[2]; wdst[3] = wsrc[3];
    }
    {
        int row = t >> 2;
        int c0 = (t & 3) * 16;
        int grow = n0 + row;
        float4* xd = (float4*)(Xs + row * XS_STRIDE + c0);
        if (grow < N_NODES) {
            const float4* xp = (const float4*)(X + (size_t)grow * D + c0);
            xd[0] = xp[0]; xd[1] = xp[1]; xd[2] = xp[2]; xd[3] = xp[3];
        } else {
            float4 z = {0.f, 0.f, 0.f, 0.f};
            xd[0] = z; xd[1] = z; xd[2] = z; xd[3] = z;
        }
    }
    __syncthreads();

    int tc = t & 15, tr = t >> 4;
    int r0 = tr * 4, c0 = tc * 4;
    float acc[4][4] = {};
    #pragma unroll 4
    for (int k = 0; k < 64; k++) {
        float4 wv = *(const float4*)&Ws[k * 64 + c0];
        #pragma unroll
        for (int i = 0; i < 4; i++) {
            float xv = Xs[(r0 + i) * XS_STRIDE + k];
            acc[i][0] = fmaf(xv, wv.x, acc[i][0]);
            acc[i][1] = fmaf(xv, wv.y, acc[i][1]);
            acc[i][2] = fmaf(xv, wv.z, acc[i][2]);
            acc[i][3] = fmaf(xv, wv.w, acc[i][3]);
        }
    }
    #pragma unroll
    for (int i = 0; i < 4; i++) {
        int grow = n0 + r0 + i;
        if (grow < N_NODES) {
            float dsc = dis[grow];
            h4 o;
            o.x = (_Float16)(acc[i][0] * dsc);
            o.y = (_Float16)(acc[i][1] * dsc);
            o.z = (_Float16)(acc[i][2] * dsc);
            o.w = (_Float16)(acc[i][3] * dsc);
            *(h4*)&G16[(size_t)grow * D + c0] = o;
        }
    }
}

// ---------- aggregation: fp16 gather table, f32 accumulate ----------
// 16-lane group per node (lane owns 4 features = 8B of the 128B row).
// 8-deep predicated edge walk -> 8 gathers in flight per lane.

__global__ __launch_bounds__(256) void k_agg(
        const _Float16* __restrict__ G16, const int* __restrict__ rstart,
        const int* __restrict__ rend, const int* __restrict__ col,
        const float* __restrict__ dis, const float* __restrict__ bias,
        float* __restrict__ Out) {
    int t = threadIdx.x;
    int grp = t >> 4;                 // 16 node-groups per block
    int fl4 = (t & 15) * 4;           // feature offset (4 feats per lane)
    int n = blockIdx.x * 16 + grp;    // grid = 3125 -> n < 50000 always

    int s = rstart[n], e = rend[n];
    f4 acc = __builtin_convertvector(*(const h4*)(G16 + (size_t)n * D + fl4), f4);

    for (int i = s; i < e; i += 8) {
        int i1 = i + 1, i2 = i + 2, i3 = i + 3;
        int i4 = i + 4, i5 = i + 5, i6 = i + 6, i7 = i + 7;
        int c0 = col[i];
        int c1 = col[i1 < e ? i1 : i];
        int c2 = col[i2 < e ? i2 : i];
        int c3 = col[i3 < e ? i3 : i];
        int c4 = col[i4 < e ? i4 : i];
        int c5 = col[i5 < e ? i5 : i];
        int c6 = col[i6 < e ? i6 : i];
        int c7 = col[i7 < e ? i7 : i];
        float f1 = (i1 < e) ? 1.f : 0.f;
        float f2 = (i2 < e) ? 1.f : 0.f;
        float f3 = (i3 < e) ? 1.f : 0.f;
        float f4_ = (i4 < e) ? 1.f : 0.f;
        float f5 = (i5 < e) ? 1.f : 0.f;
        float f6 = (i6 < e) ? 1.f : 0.f;
        float f7 = (i7 < e) ? 1.f : 0.f;
        f4 g0 = __builtin_convertvector(*(const h4*)(G16 + (size_t)c0 * D + fl4), f4);
        f4 g1 = __builtin_convertvector(*(const h4*)(G16 + (size_t)c1 * D + fl4), f4);
        f4 g2 = __builtin_convertvector(*(const h4*)(G16 + (size_t)c2 * D + fl4), f4);
        f4 g3 = __builtin_convertvector(*(const h4*)(G16 + (size_t)c3 * D + fl4), f4);
        f4 g4 = __builtin_convertvector(*(const h4*)(G16 + (size_t)c4 * D + fl4), f4);
        f4 g5 = __builtin_convertvector(*(const h4*)(G16 + (size_t)c5 * D + fl4), f4);
        f4 g6 = __builtin_convertvector(*(const h4*)(G16 + (size_t)c6 * D + fl4), f4);
        f4 g7 = __builtin_convertvector(*(const h4*)(G16 + (size_t)c7 * D + fl4), f4);
        acc += g0;
        acc += f1 * g1;
        acc += f2 * g2;
        acc += f3 * g3;
        acc += f4_ * g4;
        acc += f5 * g5;
        acc += f6 * g6;
        acc += f7 * g7;
    }

    float dsc = dis[n];
    f4 bv = *(const f4*)(bias + fl4);
    f4 o = dsc * acc + bv;
    *(f4*)(Out + (size_t)n * D + fl4) = o;
}

// ---------- pooling (bounds fused via inline binary search) ----------

__device__ __forceinline__ int lower_bound_batch(const int* batch, int g) {
    int lo = 0, hi = N_NODES;
    while (lo < hi) {
        int mid = (lo + hi) >> 1;
        if (batch[mid] < g) lo = mid + 1; else hi = mid;
    }
    return lo;
}

__global__ __launch_bounds__(256) void k_pool(
        const float* __restrict__ H, const int* __restrict__ batch,
        float* __restrict__ P) {
    int g = blockIdx.x * 4 + (threadIdx.x >> 6);
    if (g >= N_GRAPHS) return;
    int lane = threadIdx.x & 63;
    int es  = lane >> 4;
    int fg4 = (lane & 15) * 4;
    int s = lower_bound_batch(batch, g);
    int e = lower_bound_batch(batch, g + 1);
    float4 acc = {0.f, 0.f, 0.f, 0.f};
    for (int r = s + es; r < e; r += 4) {
        float4 h = *(const float4*)(H + (size_t)r * D + fg4);
        acc.x += h.x; acc.y += h.y; acc.z += h.z; acc.w += h.w;
    }
    #pragma unroll
    for (int m = 16; m < 64; m <<= 1) {
        acc.x += __shfl_xor(acc.x, m, 64);
        acc.y += __shfl_xor(acc.y, m, 64);
        acc.z += __shfl_xor(acc.z, m, 64);
        acc.w += __shfl_xor(acc.w, m, 64);
    }
    int cntr = e - s;
    float inv = 1.0f / (float)(cntr > 0 ? cntr : 1);
    if (es == 0) {
        float4 o;
        o.x = acc.x * inv; o.y = acc.y * inv; o.z = acc.z * inv; o.w = acc.w * inv;
        *(float4*)(P + g * D + fg4) = o;
    }
}

// ---------- classifier MLP ----------

__global__ __launch_bounds__(128) void k_mlp(
        const float* __restrict__ P,
        const float* __restrict__ w1, const float* __restrict__ b1,
        const float* __restrict__ w2, const float* __restrict__ b2,
        const float* __restrict__ fcw, const float* __restrict__ fcb,
        float* __restrict__ out) {
    __shared__ float ps[64];
    __shared__ float red[128];
    int g = blockIdx.x, t = threadIdx.x;
    if (t < 64) ps[t] = P[g * D + t];
    __syncthreads();
    float acc = b1[t];
    #pragma unroll
    for (int k = 0; k < 64; k++) acc = fmaf(ps[k], w1[k * D_CLS + t], acc);
    red[t] = acc * w2[t];
    __syncthreads();
    for (int s2 = 64; s2 > 0; s2 >>= 1) {
        if (t < s2) red[t] += red[t + s2];
        __syncthreads();
    }
    if (t == 0) {
        float o = red[0] + b2[0];
        o = fmaf(o, fcw[0], fcb[0]);
        out[g] = (o >= 0.f) ? o : 0.01f * o;
    }
}

// ---------- launch ----------

extern "C" void kernel_launch(void* const* d_in, const int* in_sizes, int n_in,
                              void* d_out, int out_size, void* d_ws, size_t ws_size,
                              hipStream_t stream) {
    const float* x   = (const float*)d_in[0];
    const float* W0  = (const float*)d_in[1];
    const float* b0  = (const float*)d_in[2];
    const float* W1  = (const float*)d_in[3];
    const float* b1  = (const float*)d_in[4];
    const float* W2  = (const float*)d_in[5];
    const float* b2  = (const float*)d_in[6];
    const float* l1w = (const float*)d_in[7];
    const float* l1b = (const float*)d_in[8];
    const float* l2w = (const float*)d_in[9];
    const float* l2b = (const float*)d_in[10];
    const float* fcw = (const float*)d_in[11];
    const float* fcb = (const float*)d_in[12];
    const int* eidx  = (const int*)d_in[13];
    const int* batch = (const int*)d_in[14];
    const int* src = eidx;
    const int* dst = eidx + N_EDGES;

    char* ws = (char*)d_ws;
    size_t off = 0;
    auto alloc = [&](size_t bytes) -> void* {
        off = (off + 255) & ~(size_t)255;
        void* p = ws + off;
        off += bytes;
        return p;
    };

    int*   rstart = (int*)  alloc(N_NODES * sizeof(int));
    int*   rend   = (int*)  alloc(N_NODES * sizeof(int));
    int*   btail  = (int*)  alloc(NBUK * sizeof(int));
    int*   ebuf   = (int*)  alloc((size_t)NBUK * BSTRIDE * sizeof(int));
    int*   col    = (int*)  alloc((size_t)NBUK * BSTRIDE * sizeof(int));
    float* dis    = (float*)alloc(N_NODES * sizeof(float));
    _Float16* G16 = (_Float16*)alloc((size_t)N_NODES * D * sizeof(_Float16));
    float* bufB   = (float*)alloc((size_t)N_NODES * D * sizeof(float));
    float* bufC   = (float*)alloc((size_t)N_NODES * D * sizeof(float));
    float* pooled = (float*)alloc((size_t)N_GRAPHS * D * sizeof(float));

    const int nbPart = cdiv(N_EDGES, PART_TILE);   // 196

    k_binit<<<cdiv(NBUK, 256), 256, 0, stream>>>(btail);
    k_part<<<nbPart, 256, 0, stream>>>(src, dst, btail, ebuf);
    k_build<<<NBUK, 256, 0, stream>>>(ebuf, btail, rstart, rend, dis, col);

    const int nbGemm = cdiv(N_NODES, 64);    // 782
    const int nbAgg  = cdiv(N_NODES, 16);    // 3125

    // layer 0: x -> B
    k_gemm_scale<<<nbGemm, 256, 0, stream>>>(x, W0, dis, G16);
    k_agg<<<nbAgg, 256, 0, stream>>>(G16, rstart, rend, col, dis, b0, bufB);
    // layer 1: B -> C
    k_gemm_scale<<<nbGemm, 256, 0, stream>>>(bufB, W1, dis, G16);
    k_agg<<<nbAgg, 256, 0, stream>>>(G16, rstart, rend, col, dis, b1, bufC);
    // layer 2: C -> B
    k_gemm_scale<<<nbGemm, 256, 0, stream>>>(bufC, W2, dis, G16);
    k_agg<<<nbAgg, 256, 0, stream>>>(G16, rstart, rend, col, dis, b2, bufB);

    k_pool<<<cdiv(N_GRAPHS, 4), 256, 0, stream>>>(bufB, batch, pooled);
    k_mlp<<<N_GRAPHS, 128, 0, stream>>>(pooled, l1w, l1b, l2w, l2b, fcw, fcb,
                                        (float*)d_out);
}